// Round 3
// baseline (1477.151 us; speedup 1.0000x reference)
//
#include <hip/hip_runtime.h>
#include <hip/hip_bf16.h>

// Problem constants (from reference): B=64, NCLS=200 -> BN rows = 12800
#define BROWS  12800
#define TSTEPS 8
#define EMB    300
#define EMBP   384          // EMB padded to /128 so K1 has an EVEN tile count
#define RNN    512
#define NG     2048         // 4*RNN gate width
#define K1     896          // EMBP + RNN  (layer-1 concat GEMM K), 14 tiles (even)
#define K2     1024         // RNN + RNN   (layer-2 concat GEMM K), 16 tiles (even)

typedef short bf16x8 __attribute__((ext_vector_type(8)));   // 8 bf16 in 4 VGPRs
typedef float f32x4  __attribute__((ext_vector_type(4)));
typedef __hip_bfloat16 bf16;

__device__ __forceinline__ float sigmoidf_(float x) { return 1.f / (1.f + __expf(-x)); }
__device__ __forceinline__ float tanhf_(float x)    { return 1.f - 2.f / (__expf(2.f * x) + 1.f); }

// async global->LDS, 16B per lane. LDS dest = wave-uniform base + lane*16.
__device__ __forceinline__ void gl_lds16(const bf16* g, bf16* l) {
    __builtin_amdgcn_global_load_lds(
        (const __attribute__((address_space(1))) void*)g,
        (__attribute__((address_space(3))) void*)l,
        16, 0, 0);
}

// ---------------------------------------------------------------------------
// Weight repack: fp32 -> bf16, K-concat LINEAR row-major [N=2048][K],
// GATE-INTERLEAVED row permutation: output row n encodes
//   w = n&15 (unit), g = (n>>4)&3 (gate i,f,g,o), b = n>>6 (unit group)
//   original row = g*512 + b*16 + w
// => each wave's 64-col span = [i|f|g|o] of the same 16 units.
// K1 layout: k<300 = Wih1, 300<=k<384 = zero pad, k>=384 = Whh1[k-384].
// ---------------------------------------------------------------------------
__global__ void convert_weights(const float* __restrict__ Wih1, const float* __restrict__ Whh1,
                                const float* __restrict__ Wih2, const float* __restrict__ Whh2,
                                const float* __restrict__ bih1, const float* __restrict__ bhh1,
                                const float* __restrict__ bih2, const float* __restrict__ bhh2,
                                bf16* __restrict__ Wc1, bf16* __restrict__ Wc2,
                                float* __restrict__ Bp1, float* __restrict__ Bp2) {
    int idx = blockIdx.x * 256 + threadIdx.x;
    const int n1 = NG * K1;   // 1,835,008
    const int n2 = NG * K2;   // 2,097,152
    if (idx < n1) {
        int n = idx / K1, k = idx - n * K1;
        int on = ((n >> 4) & 3) * RNN + (n >> 6) * 16 + (n & 15);
        float v = 0.f;
        if (k < EMB)        v = Wih1[on * EMB + k];
        else if (k >= EMBP) v = Whh1[on * RNN + (k - EMBP)];
        Wc1[idx] = __float2bfloat16(v);
    }
    if (idx < n2) {
        int n = idx >> 10, k = idx & (K2 - 1);
        int on = ((n >> 4) & 3) * RNN + (n >> 6) * 16 + (n & 15);
        float v = (k < RNN) ? Wih2[on * RNN + k] : Whh2[on * RNN + (k - RNN)];
        Wc2[idx] = __float2bfloat16(v);
    }
    if (idx < NG) {
        int on = ((idx >> 4) & 3) * RNN + (idx >> 6) * 16 + (idx & 15);
        Bp1[idx] = bih1[on] + bhh1[on];
        Bp2[idx] = bih2[on] + bhh2[on];
    }
}

// ---------------------------------------------------------------------------
// Embedding gather + tanh -> Xbuf [BROWS][384] (cols 300..383 zero pad).
// ---------------------------------------------------------------------------
__global__ void embed_step(const int* __restrict__ sent, const float* __restrict__ w2v,
                           bf16* __restrict__ Xbuf, int t) {
    int row = blockIdx.x;
    int col = threadIdx.x;                 // 0..383
    int id  = sent[row * TSTEPS + t];
    float v = (col < EMB) ? tanhf_(w2v[id * EMB + col]) : 0.f;
    Xbuf[(size_t)row * EMBP + col] = __float2bfloat16(v);
}

// ---------------------------------------------------------------------------
// ROUND-10: 8-phase/2-tile schedule with AGE-CORRECT counted vmcnt.
//
// ROUND-9 POST-MORTEM: vmcnt(4) at ph4/ph8 confirmed loads issued ONE phase
// earlier (outstanding queue was 12, newest-4 kept) -> ~600+ cyc raw-latency
// stall twice per iteration with 1 block/CU and nothing to hide it. This
// round re-derives staging slots so every confirmed load is >=4 phases old
// and >=8 loads stay in flight at every checkpoint (true T4).
//
// Reads per tile (par p): ph1 A0-3+B0-1, ph2 B2-3, ph3 A4-7.
//  => B(p) region free after ph2-bar; A(p) region free after ph3-bar.
// Staging (iter reads tiles u=2i (p0), u+1 (p1)):
//   ph3: B-lo(u+2)                       [B(p0) freed at ph2-bar]
//   ph4: B-hi(u+2), A-lo(u+2), A-hi(u+2) [A(p0) freed at ph3-bar]
//        vmcnt(8): confirms tile u+1 (staged prev ph7/8, age 4-5 phases),
//        keeps tile u+2's 8 loads in flight
//   ph7: B-lo(u+3)                       [B(p1) freed at ph6-bar]
//   ph8: B-hi(u+3), A-lo(u+3), A-hi(u+3) [A(p1) freed at ph7-bar]
//        vmcnt(8): confirms tile u+2 (age 4-5), keeps tile u+3 in flight
// Queue never drops below 8 outstanding mid-loop. Last iter stages nothing:
// ph4 vmcnt(0) drains tile NT-1 (all loads age>=5, cheap).
// Prologue: stage tiles 0,1 (16 loads); vmcnt(8) confirms tile 0.
//
// Per-phase cadence (T3+T5): reads+stage, BAR, lgkm(0)+sched_barrier
// (rule #18), setprio(1), 16-MFMA pure burst, setprio(0), [vmcnt], BAR.
// All ds_reads are imm-offset off 8 precomputed base VGPRs.
//
// Epilogue: unchanged round-3 fused LSTM; h via LDS transpose (stride 72)
// for coalesced 16B stores. T1: bijective XCD swizzle over 400 blocks.
// ---------------------------------------------------------------------------
#define BM 256
#define BN 256

#define BAR()   __builtin_amdgcn_s_barrier()
#define SP1     __builtin_amdgcn_s_setprio(1)
#define SP0     __builtin_amdgcn_s_setprio(0)
#define LGKM0() do { asm volatile("s_waitcnt lgkmcnt(0)" ::: "memory"); \
                     __builtin_amdgcn_sched_barrier(0); } while (0)
#define VMC(n)  do { asm volatile("s_waitcnt vmcnt(" #n ")" ::: "memory"); \
                     __builtin_amdgcn_sched_barrier(0); } while (0)

// ds_read fragment groups (constant par/idx -> imm-offset ds_read_b128)
#define DSA(h2, par) do { _Pragma("unroll") for (int i2 = 0; i2 < 4; ++i2) \
    _Pragma("unroll") for (int kk2 = 0; kk2 < 2; ++kk2) \
        af[(h2)*4+i2][kk2] = *(const bf16x8*)(adrA[par][kk2] + ((h2)*4+i2)*1024); } while (0)
#define DSB(h2, par) do { _Pragma("unroll") for (int j2 = 0; j2 < 2; ++j2) \
    _Pragma("unroll") for (int kk2 = 0; kk2 < 2; ++kk2) \
        bfr[(h2)*2+j2][kk2] = *(const bf16x8*)(adrB[par][kk2] + ((h2)*2+j2)*1024); } while (0)
// one C-quadrant x K=64: 16 MFMA pure burst
#define MFQ(ih, jh) do { _Pragma("unroll") for (int kk2 = 0; kk2 < 2; ++kk2) \
    _Pragma("unroll") for (int i2 = 0; i2 < 4; ++i2) \
    _Pragma("unroll") for (int j2 = 0; j2 < 2; ++j2) \
        acc[(ih)*4+i2][(jh)*2+j2] = __builtin_amdgcn_mfma_f32_16x16x32_bf16( \
            af[(ih)*4+i2][kk2], bfr[(jh)*2+j2][kk2], acc[(ih)*4+i2][(jh)*2+j2], 0, 0, 0); } while (0)

__global__ __launch_bounds__(512, 2) void gemm_lstm(
        const bf16* __restrict__ Ax, int ldx, int ksplit,
        const bf16* __restrict__ Ah, int ldh_in,
        const bf16* __restrict__ W,
        const float* __restrict__ Bp,
        float* __restrict__ cst,
        bf16* __restrict__ hdst, int ldh_out, int offh,
        float* __restrict__ outf, int en_out,
        int K) {
    extern __shared__ __attribute__((aligned(16))) bf16 sh[];   // 131072 B

    const int tid  = threadIdx.x;
    const int lane = tid & 63;
    const int wave = tid >> 6;              // 0..7
    const int wm   = wave >> 2, wn = wave & 3;

    // T1: XCD-aware bijective swizzle (grid 8x50 = 400 blocks, x fastest)
    const int p0g = blockIdx.y * 8 + blockIdx.x;
    const int lb  = (p0g & 7) * 50 + (p0g >> 3);
    const int bn  = lb & 7;                 // gate-col block
    const int bm  = lb >> 3;                // row block

    const int r = lane & 15, q = lane >> 4;
    const int NITER = K >> 7;               // 2 K-tiles per iteration
    const int NT    = K >> 6;               // K-tiles total

    f32x4 acc[8][4];
#pragma unroll
    for (int i = 0; i < 8; ++i)
#pragma unroll
        for (int j = 0; j < 4; ++j)
#pragma unroll
            for (int rr = 0; rr < 4; ++rr) acc[i][j][rr] = 0.f;

    // staging geometry: chunk ch = c*512+tid; row = ch>>3 in [0,128);
    // global k-chunk = (ch&7)^(row&7); LDS dest linear (ch*8 elements)
    int srow[2], scol[2];
#pragma unroll
    for (int c = 0; c < 2; ++c) {
        int ch = c * 512 + tid;
        srow[c] = ch >> 3;
        scol[c] = ((ch & 7) ^ (srow[c] & 7)) * 8;
    }

    // 8 LDS read-base pointers: [parity][kk]; all frag reads use imm offsets
    const bf16* adrA[2][2];
    const bf16* adrB[2][2];
#pragma unroll
    for (int par = 0; par < 2; ++par)
#pragma unroll
        for (int kk = 0; kk < 2; ++kk) {
            int x = ((q + 4 * kk) ^ (r & 7)) * 8;
            adrA[par][kk] = sh + par * 32768 + wm * 8192 + r * 64 + x;
            adrB[par][kk] = sh + par * 32768 + 16384 + (wn >> 1) * 8192 + (wn & 1) * 4096
                               + r * 64 + x;
        }

    auto stage_half_A = [&](int tile, int half) {
        int kb = tile << 6;
        const bf16* src; int ld, ko;
        if (kb < ksplit) { src = Ax; ld = ldx;    ko = kb; }
        else             { src = Ah; ld = ldh_in; ko = kb - ksplit; }
        src += (size_t)(bm * BM + half * 128) * ld;
        bf16* dst = sh + (tile & 1) * 32768 + half * 8192;
#pragma unroll
        for (int c = 0; c < 2; ++c)
            gl_lds16(src + (size_t)srow[c] * ld + ko + scol[c],
                     dst + (c * 512 + tid) * 8);
    };
    auto stage_half_B = [&](int tile, int half) {
        const bf16* src = W + (size_t)(bn * BN + half * 128) * K + (tile << 6);
        bf16* dst = sh + (tile & 1) * 32768 + 16384 + half * 8192;
#pragma unroll
        for (int c = 0; c < 2; ++c)
            gl_lds16(src + (size_t)srow[c] * K + scol[c],
                     dst + (c * 512 + tid) * 8);
    };

    // prologue: tiles 0 and 1 fully staged (16 loads); vmcnt(8) confirms
    // tile 0 while tile 1's 8 loads stay in flight
    stage_half_A(0, 0); stage_half_A(0, 1);
    stage_half_B(0, 0); stage_half_B(0, 1);
    stage_half_A(1, 0); stage_half_A(1, 1);
    stage_half_B(1, 0); stage_half_B(1, 1);
    VMC(8);
    BAR();

    bf16x8 af[8][2], bfr[4][2];
    for (int it = 0; it < NITER; ++it) {
        const int u = it * 2;
        const bool s2 = (u + 2 < NT);       // stage tile u+2 this iter?
        const bool s3 = (u + 3 < NT);       // stage tile u+3 this iter?

        // ---- ph1: A0-3(p0)+B0-1(p0)
        DSA(0, 0); DSB(0, 0);
        BAR(); LGKM0();
        SP1; MFQ(0, 0); SP0;
        BAR();
        // ---- ph2: B2-3(p0)                       [B(p0) free after this]
        DSB(1, 0);
        BAR(); LGKM0();
        SP1; MFQ(0, 1); SP0;
        BAR();
        // ---- ph3: A4-7(p0); stage B-lo(u+2)      [A(p0) free after this]
        DSA(1, 0);
        if (s2) stage_half_B(u + 2, 0);
        BAR(); LGKM0();
        SP1; MFQ(1, 0); SP0;
        BAR();
        // ---- ph4: stage B-hi,A-lo,A-hi(u+2); confirm tile u+1 (age 4-5)
        if (s2) { stage_half_B(u + 2, 1); stage_half_A(u + 2, 0); stage_half_A(u + 2, 1); }
        BAR(); LGKM0();
        SP1; MFQ(1, 1); SP0;
        if (s2) { VMC(8); } else { VMC(0); }
        BAR();
        // ---- ph5: A0-3(p1)+B0-1(p1)
        DSA(0, 1); DSB(0, 1);
        BAR(); LGKM0();
        SP1; MFQ(0, 0); SP0;
        BAR();
        // ---- ph6: B2-3(p1)                       [B(p1) free after this]
        DSB(1, 1);
        BAR(); LGKM0();
        SP1; MFQ(0, 1); SP0;
        BAR();
        // ---- ph7: A4-7(p1); stage B-lo(u+3)      [A(p1) free after this]
        DSA(1, 1);
        if (s3) stage_half_B(u + 3, 0);
        BAR(); LGKM0();
        SP1; MFQ(1, 0); SP0;
        BAR();
        // ---- ph8: stage B-hi,A-lo,A-hi(u+3); confirm tile u+2 (age 4-5)
        if (s3) { stage_half_B(u + 3, 1); stage_half_A(u + 3, 0); stage_half_A(u + 3, 1); }
        BAR(); LGKM0();
        SP1; MFQ(1, 1); SP0;
        if (s3) { VMC(8); } else { VMC(0); }
        BAR();
    }
    __syncthreads();   // loop fully drained; LDS reusable as h-xpose buffer

    // ---- fused LSTM epilogue ----
    // C/D mapping (m89/m91-verified): col = lane&15, row = (lane>>4)*4 + reg
    const int colb = bn * BN + wn * 64;
    const int u    = (bn * 4 + wn) * 16 + r;       // global unit index 0..511
    const float bi  = Bp[colb + r];
    const float bff = Bp[colb + 16 + r];
    const float bg  = Bp[colb + 32 + r];
    const float bo  = Bp[colb + 48 + r];

    float cc[8][4];
#pragma unroll
    for (int i = 0; i < 8; ++i)
#pragma unroll
        for (int rr = 0; rr < 4; ++rr) {
            int row = bm * BM + wm * 128 + i * 16 + q * 4 + rr;
            cc[i][rr] = cst[(size_t)row * RNN + u];
        }

#define HLD 72   // h-xpose row stride: 144B rows (16B-aligned)
#pragma unroll
    for (int i = 0; i < 8; ++i) {
#pragma unroll
        for (int rr = 0; rr < 4; ++rr) {
            int rowl = wm * 128 + i * 16 + q * 4 + rr;       // row in block
            int row  = bm * BM + rowl;
            size_t cidx = (size_t)row * RNN + u;
            float gi = acc[i][0][rr] + bi;
            float gf = acc[i][1][rr] + bff;
            float gg = acc[i][2][rr] + bg;
            float go = acc[i][3][rr] + bo;
            float cn = sigmoidf_(gf) * cc[i][rr] + sigmoidf_(gi) * tanhf_(gg);
            float h  = sigmoidf_(go) * tanhf_(cn);
            cst[cidx] = cn;
            if (en_out) outf[cidx] = h;
            sh[rowl * HLD + wn * 16 + r] = __float2bfloat16(h);
        }
    }
    __syncthreads();

    // coalesced h stores: 256 rows x 64 units bf16; 16B x 2048 chunks
#pragma unroll
    for (int hh = 0; hh < 4; ++hh) {
        int t2   = hh * 512 + tid;         // 0..2047
        int rowl = t2 >> 3;                // 0..255
        int c8   = (t2 & 7) * 8;           // 0..56
        uint4 v  = *(const uint4*)&sh[rowl * HLD + c8];
        int row  = bm * BM + rowl;
        int gcol = bn * 64 + c8;           // unit col within [0,512)
        *(uint4*)&hdst[(size_t)row * ldh_out + offh + gcol] = v;
    }
#undef HLD
}

// ---------------------------------------------------------------------------
// Workspace layout (all 16B-aligned; total 122,568,704 B):
//   c1   fp32 [12800][512]   off 0              (26,214,400)
//   c2   fp32 [12800][512]   off  26,214,400    (26,214,400)
//   A2a  bf16 [12800][1024]  off  52,428,800    (26,214,400)
//   A2b  bf16 [12800][1024]  off  78,643,200    (26,214,400)
//   Xbuf bf16 [12800][384]   off 104,857,600    ( 9,830,400)
//   Wc1  bf16 [2048][896]    off 114,688,000    ( 3,670,016)
//   Wc2  bf16 [2048][1024]   off 118,358,016    ( 4,194,304)
//   Bp1  fp32 [2048]         off 122,552,320    (     8,192)
//   Bp2  fp32 [2048]         off 122,560,512    (     8,192)
// First 104,857,600 B (c1,c2,A2a,A2b) zeroed each call: c(-1)=0, h(-1)=0.
// Ping-pong unchanged: L1(t) reads A2[prv][0,512), writes A2[cur][0,512);
// L2(t) reads A2[cur], writes A2[prv][512,1024). No dispatch reads and
// writes the same buffer.
// ---------------------------------------------------------------------------
extern "C" void kernel_launch(void* const* d_in, const int* in_sizes, int n_in,
                              void* d_out, int out_size, void* d_ws, size_t ws_size,
                              hipStream_t stream) {
    (void)in_sizes; (void)n_in; (void)out_size; (void)ws_size;
    const int*   sent = (const int*)d_in[0];
    const float* w2v  = (const float*)d_in[1];
    const float* Wih1 = (const float*)d_in[2];
    const float* Whh1 = (const float*)d_in[3];
    const float* bih1 = (const float*)d_in[4];
    const float* bhh1 = (const float*)d_in[5];
    const float* Wih2 = (const float*)d_in[6];
    const float* Whh2 = (const float*)d_in[7];
    const float* bih2 = (const float*)d_in[8];
    const float* bhh2 = (const float*)d_in[9];
    float* out = (float*)d_out;

    char* ws = (char*)d_ws;
    float* c1   = (float*)(ws);
    float* c2   = (float*)(ws + 26214400);
    bf16*  A2[2];
    A2[0] = (bf16*)(ws + 52428800);
    A2[1] = (bf16*)(ws + 78643200);
    bf16*  Xbuf = (bf16*) (ws + 104857600);
    bf16*  Wc1  = (bf16*) (ws + 114688000);
    bf16*  Wc2  = (bf16*) (ws + 118358016);
    float* Bp1  = (float*)(ws + 122552320);
    float* Bp2  = (float*)(ws + 122560512);

    // one-time: allow 128 KiB dynamic LDS for the GEMM kernel
    static int shmem_set = 0;
    if (!shmem_set) {
        (void)hipFuncSetAttribute((const void*)gemm_lstm,
                                  hipFuncAttributeMaxDynamicSharedMemorySize, 131072);
        shmem_set = 1;
    }

    // zero c1,c2,A2a,A2b (ws is re-poisoned 0xAA before every call)
    hipMemsetAsync(ws, 0, 104857600, stream);

    convert_weights<<<dim3((NG * K2 + 255) / 256), dim3(256), 0, stream>>>(
        Wih1, Whh1, Wih2, Whh2, bih1, bhh1, bih2, bhh2, Wc1, Wc2, Bp1, Bp2);

    for (int t = 0; t < TSTEPS; ++t) {
        const int cur = t & 1, prv = cur ^ 1;

        // x_t -> Xbuf (cols 300..383 zeroed)
        embed_step<<<dim3(BROWS), dim3(EMBP), 0, stream>>>(sent, w2v, Xbuf, t);

        // layer 1: gates = [x_t | h1(t-1)] @ Wc1^T, fused update
        gemm_lstm<<<dim3(NG / BN, BROWS / BM), dim3(512), 131072, stream>>>(
            Xbuf, EMBP, EMBP,
            A2[prv], K2,
            Wc1, Bp1, c1,
            A2[cur], K2, 0,
            (float*)nullptr, 0, K1);

        // layer 2: gates = [h1(t) | h2(t-1)] @ Wc2^T, fused update
        gemm_lstm<<<dim3(NG / BN, BROWS / BM), dim3(512), 131072, stream>>>(
            (const bf16*)nullptr, 0, 0,
            A2[cur], K2,
            Wc2, Bp2, c2,
            A2[prv], K2, RNN,
            out, (t == TSTEPS - 1) ? 1 : 0, K2);
    }
}

// Round 4
// 1145.575 us; speedup vs baseline: 1.2894x; 1.2894x over previous
//
#include <hip/hip_runtime.h>
#include <hip/hip_bf16.h>

// Problem constants (from reference): B=64, NCLS=200 -> BN rows = 12800
#define BROWS  12800
#define TSTEPS 8
#define EMB    300
#define EMBP   320          // EMB padded to /32, x-slot width
#define RNN    512
#define NG     2048         // 4*RNN gate width
#define K1     832          // EMBP + RNN  (layer-1 concat GEMM K), 13*64
#define K2     1024         // RNN + RNN   (layer-2 concat GEMM K), 16*64

typedef short bf16x8 __attribute__((ext_vector_type(8)));   // 8 bf16 in 4 VGPRs (m89-verified operand type)
typedef float f32x4  __attribute__((ext_vector_type(4)));
typedef __hip_bfloat16 bf16;

__device__ __forceinline__ float sigmoidf_(float x) { return 1.f / (1.f + __expf(-x)); }
// exp-based tanh: exact saturation at +-inf, ~ulp-level error vs tanhf, one v_exp
__device__ __forceinline__ float tanhf_(float x)    { return 1.f - 2.f / (__expf(2.f * x) + 1.f); }

// async global->LDS, 16B per lane (m97). LDS dest = wave-uniform base + lane*16.
__device__ __forceinline__ void gl_lds16(const bf16* g, bf16* l) {
    __builtin_amdgcn_global_load_lds(
        (const __attribute__((address_space(1))) void*)g,
        (__attribute__((address_space(3))) void*)l,
        16, 0, 0);
}

// ---------------------------------------------------------------------------
// Weight repack (round-3 proven): fp32 -> bf16, K-concat LINEAR row-major
// [N=2048][K], GATE-INTERLEAVED row permutation: output row n encodes
//   w = n&15 (unit), g = (n>>4)&3 (gate i,f,g,o), b = n>>6 (unit group)
//   original row = g*512 + b*16 + w
// => each wave's 64-col span = [i|f|g|o] of the same 16 units (epilogue needs
// no cross-lane exchange). Emits permuted combined biases Bp = bih+bhh.
// ---------------------------------------------------------------------------
__global__ void convert_weights(const float* __restrict__ Wih1, const float* __restrict__ Whh1,
                                const float* __restrict__ Wih2, const float* __restrict__ Whh2,
                                const float* __restrict__ bih1, const float* __restrict__ bhh1,
                                const float* __restrict__ bih2, const float* __restrict__ bhh2,
                                bf16* __restrict__ Wc1, bf16* __restrict__ Wc2,
                                float* __restrict__ Bp1, float* __restrict__ Bp2) {
    int idx = blockIdx.x * 256 + threadIdx.x;
    const int n1 = NG * K1;   // 1,703,936
    const int n2 = NG * K2;   // 2,097,152
    if (idx < n1) {
        int n = idx / K1, k = idx - n * K1;
        int on = ((n >> 4) & 3) * RNN + (n >> 6) * 16 + (n & 15);
        float v = 0.f;
        if (k < EMB)        v = Wih1[on * EMB + k];
        else if (k >= EMBP) v = Whh1[on * RNN + (k - EMBP)];
        Wc1[idx] = __float2bfloat16(v);
    }
    if (idx < n2) {
        int n = idx >> 10, k = idx & (K2 - 1);
        int on = ((n >> 4) & 3) * RNN + (n >> 6) * 16 + (n & 15);
        float v = (k < RNN) ? Wih2[on * RNN + k] : Whh2[on * RNN + (k - RNN)];
        Wc2[idx] = __float2bfloat16(v);
    }
    if (idx < NG) {
        int on = ((idx >> 4) & 3) * RNN + (idx >> 6) * 16 + (idx & 15);
        Bp1[idx] = bih1[on] + bhh1[on];
        Bp2[idx] = bih2[on] + bhh2[on];
    }
}

// ---------------------------------------------------------------------------
// Embedding gather + tanh -> Xbuf [BROWS][320] (cols 300..319 zero pad).
// Written before layer-1 reads it each step; nothing else touches it.
// ---------------------------------------------------------------------------
__global__ void embed_step(const int* __restrict__ sent, const float* __restrict__ w2v,
                           bf16* __restrict__ Xbuf, int t) {
    int row = blockIdx.x;
    int col = threadIdx.x;                 // 0..319
    int id  = sent[row * TSTEPS + t];
    float v = (col < EMB) ? tanhf_(w2v[id * EMB + col]) : 0.f;
    Xbuf[(size_t)row * EMBP + col] = __float2bfloat16(v);
}

// ---------------------------------------------------------------------------
// Fused GEMM + LSTM cell update (round-3 core, RACE-FREE dataflow) — the
// VERIFIED 71us/dispatch structure. ROUNDS 8-10 POST-MORTEM: three deep-
// pipeline variants (256^2 tile, 8-wave, counted-vmcnt phase schedules) all
// regressed to 89-123us at near-ideal FETCH: with 1 block/CU and 8-16
// barriers per 2 K-tiles, the lockstep sync cost exceeds the barrier-drain
// cost this structure pays. K here is 13-16 tiles with a heavy fused
// epilogue — the deep pipeline's amortization regime does not exist. Do not
// re-attempt without a fundamentally different overlap source.
//
//   gates[M,2048] = A[M,Kl] * W[2048,Kl(ldw)]^T  (bf16 MFMA 16x16x32, fp32 acc)
// A is a virtual K-concat of two sources:
//   k <  ksplit : Ax (row stride ldx)      — layer-1 x_t, layer-2 unused
//   k >= ksplit : Ah (row stride ldh_in)   — h columns from the PREVIOUS
//                                            dispatch's buffer (ping-pong)
// Kl (loop bound) may be < ldw (W leading dim): at t=0 all h-states are 0,
// so the h-region K-tiles are skipped entirely (L1: Kl=320, L2: Kl=512).
//
// __launch_bounds__(256,4): 128-reg/thread budget. ROUND-7 LESSON: (256,5)
// caps the unified VGPR/AGPR file at ~102 regs -> spills the 64-reg
// accumulator to scratch. Never bound below the 4x4 f32x4 accumulator.
//
// Staging: both operands via global_load_lds w=16; LDS unpadded [128][64]
// with XOR chunk swizzle on the global side (zero bank conflicts).
// Epilogue: per (row,unit) c'=sig(f)*c+sig(i)*tanh(g); h=sig(o)*tanh(c');
// h routed through LDS transpose (stride 40) for coalesced global stores.
// Block 256 thr = 4 waves; tile 128x128; wave 64x64 = 4x4 MFMA tiles.
// Grid (16,100), bn fastest => same-bm blocks dispatch-adjacent (L2 sharing
// of A row-slices; breaking this adjacency was measured costly).
// ---------------------------------------------------------------------------
#define BM 128
#define BN 128

__global__ __launch_bounds__(256, 4) void gemm_lstm(const bf16* __restrict__ Ax, int ldx, int ksplit,
                                                    const bf16* __restrict__ Ah, int ldh_in,
                                                    const bf16* __restrict__ W, int ldw,
                                                    const float* __restrict__ Bp,
                                                    float* __restrict__ cst,
                                                    bf16* __restrict__ hdst, int ldh_out, int offh,
                                                    float* __restrict__ outf, int en_out,
                                                    int Kl) {
    __shared__ __attribute__((aligned(16))) bf16 sA[BM * 64];   // 16 KB (reused as h xpose buf)
    __shared__ __attribute__((aligned(16))) bf16 sB[BN * 64];   // 16 KB

    const int tid  = threadIdx.x;
    const int lane = tid & 63;
    const int wave = tid >> 6;
    const int wm   = wave >> 1, wn = wave & 1;
    const int bn   = blockIdx.x;           // 16  (gate-col blocks, fastest)
    const int bm   = blockIdx.y;           // 100 (row blocks)

    f32x4 acc[4][4];
#pragma unroll
    for (int i = 0; i < 4; ++i)
#pragma unroll
        for (int j = 0; j < 4; ++j)
#pragma unroll
            for (int r = 0; r < 4; ++r) acc[i][j][r] = 0.f;

    const int r = lane & 15, q = lane >> 4;

    // staging geometry: chunk ch = c*256+tid; row = ch>>3;
    // global k-chunk = (ch&7)^(row&7)  (XOR swizzle, zero conflicts)
    int srow[4], scol[4];
#pragma unroll
    for (int c = 0; c < 4; ++c) {
        int ch = c * 256 + tid;
        srow[c] = ch >> 3;
        scol[c] = ((ch & 7) ^ (srow[c] & 7)) * 8;
    }
    const bf16* Wbase = W + (size_t)(bn * BN) * ldw;

    for (int kb = 0; kb < Kl; kb += 64) {
        // wave-uniform source select (x-region vs h-region of the virtual A)
        const bf16* src; int ld, ko;
        if (kb < ksplit) { src = Ax; ld = ldx;    ko = kb; }
        else             { src = Ah; ld = ldh_in; ko = kb - ksplit; }
        src += (size_t)(bm * BM) * ld;
#pragma unroll
        for (int c = 0; c < 4; ++c) {
            int ch = c * 256 + tid;
            gl_lds16(src   + (size_t)srow[c] * ld  + ko + scol[c], &sA[ch * 8]);
            gl_lds16(Wbase + (size_t)srow[c] * ldw + kb + scol[c], &sB[ch * 8]);
        }
        __syncthreads();
#pragma unroll
        for (int kk = 0; kk < 64; kk += 32) {
            const int kc = kk >> 3;        // 0 or 4
            bf16x8 af[4], wf[4];
#pragma unroll
            for (int i = 0; i < 4; ++i)
                af[i] = *(const bf16x8*)(&sA[(wm * 64 + i * 16 + r) * 64 + (((q + kc) ^ (r & 7)) * 8)]);
#pragma unroll
            for (int j = 0; j < 4; ++j)
                wf[j] = *(const bf16x8*)(&sB[(wn * 64 + j * 16 + r) * 64 + (((q + kc) ^ (r & 7)) * 8)]);
#pragma unroll
            for (int i = 0; i < 4; ++i)
#pragma unroll
                for (int j = 0; j < 4; ++j)
                    acc[i][j] = __builtin_amdgcn_mfma_f32_16x16x32_bf16(
                        af[i], wf[j], acc[i][j], 0, 0, 0);
        }
        __syncthreads();
    }
    // trailing barrier: all sA reads done -> safe to reuse as h buffer

    // ---- fused LSTM epilogue ----
    // C/D mapping (m89/m91-verified): col = lane&15, row = (lane>>4)*4 + reg
    const int colb = bn * BN + wn * 64;
    const int u    = (2 * bn + wn) * 16 + r;      // global unit index 0..511
    const float bi = Bp[colb + r];
    const float bf = Bp[colb + 16 + r];
    const float bg = Bp[colb + 32 + r];
    const float bo = Bp[colb + 48 + r];

    // hoist the 16 c-loads so their latency overlaps the math below
    float cc[4][4];
#pragma unroll
    for (int i = 0; i < 4; ++i)
#pragma unroll
        for (int rr = 0; rr < 4; ++rr) {
            int row = bm * BM + wm * 64 + i * 16 + q * 4 + rr;
            cc[i][rr] = cst[(size_t)row * RNN + u];
        }

#define HLD 40   // h-xpose row stride: 80B rows (16B-aligned)
#pragma unroll
    for (int i = 0; i < 4; ++i) {
#pragma unroll
        for (int rr = 0; rr < 4; ++rr) {
            int rowl = wm * 64 + i * 16 + q * 4 + rr;       // row in block
            int row  = bm * BM + rowl;
            size_t cidx = (size_t)row * RNN + u;
            float gi = acc[i][0][rr] + bi;
            float gf = acc[i][1][rr] + bf;
            float gg = acc[i][2][rr] + bg;
            float go = acc[i][3][rr] + bo;
            float cn = sigmoidf_(gf) * cc[i][rr] + sigmoidf_(gi) * tanhf_(gg);
            float h  = sigmoidf_(go) * tanhf_(cn);
            cst[cidx] = cn;                                  // 64B segments
            if (en_out) outf[cidx] = h;
            sA[rowl * HLD + wn * 16 + r] = __float2bfloat16(h);
        }
    }
    __syncthreads();

    // coalesced h stores: 128 rows x 32 units bf16; 16B x 512 chunks
#pragma unroll
    for (int half = 0; half < 2; ++half) {
        int t    = half * 256 + tid;       // 0..511
        int rowl = t >> 2;                 // 0..127
        int c8   = (t & 3) * 8;            // 0,8,16,24
        uint4 v  = *(const uint4*)&sA[rowl * HLD + c8];
        int row  = bm * BM + rowl;
        int gcol = bn * 32 + c8;           // unit col within [0,512)
        *(uint4*)&hdst[(size_t)row * ldh_out + offh + gcol] = v;
    }
#undef HLD
}

// ---------------------------------------------------------------------------
// Workspace layout (all 16B-aligned; total 120,668,160 B):
//   c1   fp32 [12800][512]           26,214,400   offset 0
//   c2   fp32 [12800][512]           26,214,400   offset  26,214,400
//   A2a  bf16 [12800][1024]          26,214,400   offset  52,428,800
//   A2b  bf16 [12800][1024]          26,214,400   offset  78,643,200
//   Xbuf bf16 [12800][320]            8,192,000   offset 104,857,600
//   Wc1  bf16 [2048][832]             3,407,872   offset 113,049,600
//   Wc2  bf16 [2048][1024]            4,194,304   offset 116,457,472
//   Bp1  fp32 [2048]                      8,192   offset 120,651,776
//   Bp2  fp32 [2048]                      8,192   offset 120,659,968
// ROUND-11 memset cut: only c1,c2 (52 MB) are zeroed. A2a/A2b need no init
// because t=0 dispatches skip the h K-region entirely (Kl truncation):
//   L1(0): Kl=320=ksplit -> reads only Xbuf;  writes h1(0)->A2[0][0,512)
//   L2(0): Kl=512, A=A2[0] cols[0,512)=h1(0); writes h2(0)->A2[1][512,1024)
// Every later read is of a previously-written region (ping-pong invariant:
// L1(t) reads A2[prv][0,512), writes A2[cur][0,512); L2(t) reads A2[cur],
// writes A2[prv][512,1024); no dispatch reads and writes the same buffer).
// ---------------------------------------------------------------------------
extern "C" void kernel_launch(void* const* d_in, const int* in_sizes, int n_in,
                              void* d_out, int out_size, void* d_ws, size_t ws_size,
                              hipStream_t stream) {
    (void)in_sizes; (void)n_in; (void)out_size; (void)ws_size;
    const int*   sent = (const int*)d_in[0];
    const float* w2v  = (const float*)d_in[1];
    const float* Wih1 = (const float*)d_in[2];
    const float* Whh1 = (const float*)d_in[3];
    const float* bih1 = (const float*)d_in[4];
    const float* bhh1 = (const float*)d_in[5];
    const float* Wih2 = (const float*)d_in[6];
    const float* Whh2 = (const float*)d_in[7];
    const float* bih2 = (const float*)d_in[8];
    const float* bhh2 = (const float*)d_in[9];
    float* out = (float*)d_out;

    char* ws = (char*)d_ws;
    float* c1   = (float*)(ws);
    float* c2   = (float*)(ws + 26214400);
    bf16*  A2[2];
    A2[0] = (bf16*)(ws + 52428800);
    A2[1] = (bf16*)(ws + 78643200);
    bf16*  Xbuf = (bf16*) (ws + 104857600);
    bf16*  Wc1  = (bf16*) (ws + 113049600);
    bf16*  Wc2  = (bf16*) (ws + 116457472);
    float* Bp1  = (float*)(ws + 120651776);
    float* Bp2  = (float*)(ws + 120659968);

    // zero c1,c2 ONLY (ws is re-poisoned 0xAA before every call; A2 init is
    // unnecessary due to t=0 Kl truncation — see layout comment)
    hipMemsetAsync(ws, 0, 52428800, stream);

    convert_weights<<<dim3((NG * K2 + 255) / 256), dim3(256), 0, stream>>>(
        Wih1, Whh1, Wih2, Whh2, bih1, bhh1, bih2, bhh2, Wc1, Wc2, Bp1, Bp2);

    for (int t = 0; t < TSTEPS; ++t) {
        const int cur = t & 1, prv = cur ^ 1;

        // x_t -> Xbuf (cols 300..319 zeroed)
        embed_step<<<dim3(BROWS), dim3(EMBP), 0, stream>>>(sent, w2v, Xbuf, t);

        // layer 1: gates = [x_t | h1(t-1)] @ Wc1^T, fused update
        //   x from Xbuf (stride 320), h1(t-1) from A2[prv] cols [0,512)
        //   h1(t) -> A2[cur] cols [0,512)
        //   t=0: h1(-1)=0 -> skip h K-region entirely (Kl=320)
        gemm_lstm<<<dim3(NG / BN, BROWS / BM), dim3(256), 0, stream>>>(
            Xbuf, EMBP, EMBP,
            A2[prv], K2,
            Wc1, K1, Bp1, c1,
            A2[cur], K2, 0,
            (float*)nullptr, 0,
            (t == 0) ? EMBP : K1);

        // layer 2: gates = [h1(t) | h2(t-1)] @ Wc2^T, fused update
        //   whole A from A2[cur] (stride 1024); h2(t) -> A2[prv] cols [512,1024)
        //   final step also writes h2 -> out (fp32)
        //   t=0: h2(-1)=0 -> skip h2 K-region (Kl=512)
        gemm_lstm<<<dim3(NG / BN, BROWS / BM), dim3(256), 0, stream>>>(
            (const bf16*)nullptr, 0, 0,
            A2[cur], K2,
            Wc2, K2, Bp2, c2,
            A2[prv], K2, RNN,
            out, (t == TSTEPS - 1) ? 1 : 0,
            (t == 0) ? RNN : K2);
    }
}

// Round 5
// 1036.826 us; speedup vs baseline: 1.4247x; 1.1049x over previous
//
#include <hip/hip_runtime.h>
#include <hip/hip_bf16.h>

// Problem constants (from reference): B=64, NCLS=200 -> BN rows = 12800
#define BROWS  12800
#define TSTEPS 8
#define EMB    300
#define EMBP   320          // EMB padded to /32, x-slot width
#define RNN    512
#define NG     2048         // 4*RNN gate width
#define K1     832          // EMBP + RNN  (layer-1 concat GEMM K), 13*64
#define K2     1024         // RNN + RNN   (layer-2 concat GEMM K), 16*64
#define VOCAB  20000

typedef short bf16x8 __attribute__((ext_vector_type(8)));   // 8 bf16 in 4 VGPRs (m89-verified operand type)
typedef float f32x4  __attribute__((ext_vector_type(4)));
typedef __hip_bfloat16 bf16;

__device__ __forceinline__ float sigmoidf_(float x) { return 1.f / (1.f + __expf(-x)); }
// exp-based tanh: exact saturation at +-inf, ~ulp-level error vs tanhf, one v_exp
__device__ __forceinline__ float tanhf_(float x)    { return 1.f - 2.f / (__expf(2.f * x) + 1.f); }

// async global->LDS, 16B per lane (m97). LDS dest = wave-uniform base + lane*16;
// the GLOBAL source address is per-lane (enables the W2Vt id-gather below).
__device__ __forceinline__ void gl_lds16(const bf16* g, bf16* l) {
    __builtin_amdgcn_global_load_lds(
        (const __attribute__((address_space(1))) void*)g,
        (__attribute__((address_space(3))) void*)l,
        16, 0, 0);
}

// ---------------------------------------------------------------------------
// Weight repack (round-3 proven): fp32 -> bf16, K-concat LINEAR row-major
// [N=2048][K], GATE-INTERLEAVED row permutation: output row n encodes
//   w = n&15 (unit), g = (n>>4)&3 (gate i,f,g,o), b = n>>6 (unit group)
//   original row = g*512 + b*16 + w
// => each wave's 64-col span = [i|f|g|o] of the same 16 units (epilogue needs
// no cross-lane exchange). Emits permuted combined biases Bp = bih+bhh.
// ---------------------------------------------------------------------------
__global__ void convert_weights(const float* __restrict__ Wih1, const float* __restrict__ Whh1,
                                const float* __restrict__ Wih2, const float* __restrict__ Whh2,
                                const float* __restrict__ bih1, const float* __restrict__ bhh1,
                                const float* __restrict__ bih2, const float* __restrict__ bhh2,
                                bf16* __restrict__ Wc1, bf16* __restrict__ Wc2,
                                float* __restrict__ Bp1, float* __restrict__ Bp2) {
    int idx = blockIdx.x * 256 + threadIdx.x;
    const int n1 = NG * K1;   // 1,703,936
    const int n2 = NG * K2;   // 2,097,152
    if (idx < n1) {
        int n = idx / K1, k = idx - n * K1;
        int on = ((n >> 4) & 3) * RNN + (n >> 6) * 16 + (n & 15);
        float v = 0.f;
        if (k < EMB)        v = Wih1[on * EMB + k];
        else if (k >= EMBP) v = Whh1[on * RNN + (k - EMBP)];
        Wc1[idx] = __float2bfloat16(v);
    }
    if (idx < n2) {
        int n = idx >> 10, k = idx & (K2 - 1);
        int on = ((n >> 4) & 3) * RNN + (n >> 6) * 16 + (n & 15);
        float v = (k < RNN) ? Wih2[on * RNN + k] : Whh2[on * RNN + (k - RNN)];
        Wc2[idx] = __float2bfloat16(v);
    }
    if (idx < NG) {
        int on = ((idx >> 4) & 3) * RNN + (idx >> 6) * 16 + (idx & 15);
        Bp1[idx] = bih1[on] + bhh1[on];
        Bp2[idx] = bih2[on] + bhh2[on];
    }
}

// ---------------------------------------------------------------------------
// ROUND-12: one-time tanh(word2vec) table, bf16 [VOCAB][320] (cols 300..319
// zero). tanh(w2v) is input-only data -> computed ONCE instead of per-step
// embed_step gathers. L1's x-region staging then gathers rows of this table
// directly via per-lane global_load_lds sources (embed_step kernel deleted).
// Same numerics as the old path: tanh in fp32, then bf16 round.
// ---------------------------------------------------------------------------
__global__ void tanh_w2v(const float* __restrict__ w2v, bf16* __restrict__ W2Vt) {
    int row = blockIdx.x;
    int col = threadIdx.x;                 // 0..319
    float v = (col < EMB) ? tanhf_(w2v[row * EMB + col]) : 0.f;
    W2Vt[(size_t)row * EMBP + col] = __float2bfloat16(v);
}

// ---------------------------------------------------------------------------
// Fused GEMM + LSTM cell update — VERIFIED 71us/dispatch inner structure
// (K-loop, XOR swizzle, epilogue byte-preserved from round-11).
// ROUNDS 8-10 POST-MORTEM (do not re-attempt): three deep-pipeline variants
// (256^2, 8-wave, counted-vmcnt) all regressed to 89-123us — with 1 block/CU
// and 8-16 barriers per 2 K-tiles the lockstep sync cost exceeds this
// structure's barrier-drain cost; K is only 13-16 tiles w/ heavy epilogue.
//
// ROUND-12 DISPATCH-GRAPH RESTRUCTURE:
//  (a) ROLE-MERGED dispatch: L2(t) and L1(t+1) are independent —
//        L2(t):  reads A2[cur][0,1024),  writes A2[prv][512,1024) + c2
//        L1(t+1):reads A2[cur][0,512),   writes A2[prv][0,512)    + c1
//      disjoint writes, no read/write overlap => run as ONE dispatch with
//      gridDim.z=2; role = blockIdx.z + role_base (wave-uniform selects).
//      16 GEMM dispatches -> 9 (7 launch boundaries + tails removed).
//  (b) X-GATHER staging: L1's x-region (kb<ksplit) stages straight from the
//      pre-tanh'd W2Vt table with per-lane row ids (sent[grow*8+t]); ids
//      loaded once per block (4 ints/thread, 8-lane broadcast). Each 8-lane
//      group reads 128 contiguous bytes of a W2Vt row; table is L3-resident.
//      embed_step + Xbuf round-trip deleted.
//
// __launch_bounds__(256,4): 128-reg budget (ROUND-7: (256,5) spills the
// 64-reg accumulator). Block 256 thr = 4 waves; tile 128x128; wave 64x64.
// Grid (16,100,z), bn fastest => same-bm blocks dispatch-adjacent (L2
// sharing of A row-slices proven to matter).
// ---------------------------------------------------------------------------
#define BM 128
#define BN 128

__global__ __launch_bounds__(256, 4) void gemm_lstm(
        int role_base, int t,
        const bf16* __restrict__ W2Vt, const int* __restrict__ sent,
        const bf16* __restrict__ Asrc,   // A2[cur] panel, ld = K2
        bf16* __restrict__ hdst,         // A2[prv], ld = K2; offh by role
        const bf16* __restrict__ Wc1, const bf16* __restrict__ Wc2,
        const float* __restrict__ Bp1, const float* __restrict__ Bp2,
        float* __restrict__ cst1, float* __restrict__ cst2,
        float* __restrict__ outf, int en_out,
        int Kl1, int Kl2) {
    __shared__ __attribute__((aligned(16))) bf16 sA[BM * 64];   // 16 KB (reused as h xpose buf)
    __shared__ __attribute__((aligned(16))) bf16 sB[BN * 64];   // 16 KB

    const int tid  = threadIdx.x;
    const int lane = tid & 63;
    const int wave = tid >> 6;
    const int wm   = wave >> 1, wn = wave & 1;
    const int bn   = blockIdx.x;           // 16  (gate-col blocks, fastest)
    const int bm   = blockIdx.y;           // 100 (row blocks)
    const int role = blockIdx.z + role_base;   // 0 = L2-role, 1 = L1-role

    // wave-uniform role plumbing
    const bf16*  W;  int ldw, Kl, ksplit, offh;
    const float* Bp; float* cst;
    if (role) { W = Wc1; ldw = K1; Kl = Kl1; ksplit = EMBP; offh = 0;   Bp = Bp1; cst = cst1; }
    else      { W = Wc2; ldw = K2; Kl = Kl2; ksplit = 0;    offh = RNN; Bp = Bp2; cst = cst2; }

    f32x4 acc[4][4];
#pragma unroll
    for (int i = 0; i < 4; ++i)
#pragma unroll
        for (int j = 0; j < 4; ++j)
#pragma unroll
            for (int r = 0; r < 4; ++r) acc[i][j][r] = 0.f;

    const int r = lane & 15, q = lane >> 4;

    // staging geometry: chunk ch = c*256+tid; row = ch>>3;
    // global k-chunk = (ch&7)^(row&7)  (XOR swizzle, zero conflicts)
    int srow[4], scol[4];
#pragma unroll
    for (int c = 0; c < 4; ++c) {
        int ch = c * 256 + tid;
        srow[c] = ch >> 3;
        scol[c] = ((ch & 7) ^ (srow[c] & 7)) * 8;
    }

    // x-gather ids (L1 role only): row id per staged A-row; 8 lanes share
    // each address (HW broadcast), loaded once per block
    int idv[4];
    if (role) {
#pragma unroll
        for (int c = 0; c < 4; ++c)
            idv[c] = sent[(size_t)(bm * BM + srow[c]) * TSTEPS + t];
    }

    const bf16* Wbase = W + (size_t)(bn * BN) * ldw;
    const bf16* Abase = Asrc + (size_t)(bm * BM) * K2;

    for (int kb = 0; kb < Kl; kb += 64) {
        const bool xreg = (kb < ksplit);   // wave-uniform region select
#pragma unroll
        for (int c = 0; c < 4; ++c) {
            int ch = c * 256 + tid;
            const bf16* alane = xreg
                ? W2Vt  + (size_t)idv[c] * EMBP + kb + scol[c]
                : Abase + (size_t)srow[c] * K2 + (kb - ksplit) + scol[c];
            gl_lds16(alane, &sA[ch * 8]);
            gl_lds16(Wbase + (size_t)srow[c] * ldw + kb + scol[c], &sB[ch * 8]);
        }
        __syncthreads();
#pragma unroll
        for (int kk = 0; kk < 64; kk += 32) {
            const int kc = kk >> 3;        // 0 or 4
            bf16x8 af[4], wf[4];
#pragma unroll
            for (int i = 0; i < 4; ++i)
                af[i] = *(const bf16x8*)(&sA[(wm * 64 + i * 16 + r) * 64 + (((q + kc) ^ (r & 7)) * 8)]);
#pragma unroll
            for (int j = 0; j < 4; ++j)
                wf[j] = *(const bf16x8*)(&sB[(wn * 64 + j * 16 + r) * 64 + (((q + kc) ^ (r & 7)) * 8)]);
#pragma unroll
            for (int i = 0; i < 4; ++i)
#pragma unroll
                for (int j = 0; j < 4; ++j)
                    acc[i][j] = __builtin_amdgcn_mfma_f32_16x16x32_bf16(
                        af[i], wf[j], acc[i][j], 0, 0, 0);
        }
        __syncthreads();
    }
    // trailing barrier: all sA reads done -> safe to reuse as h buffer

    // ---- fused LSTM epilogue ----
    // C/D mapping (m89/m91-verified): col = lane&15, row = (lane>>4)*4 + reg
    const int colb = bn * BN + wn * 64;
    const int u    = (2 * bn + wn) * 16 + r;      // global unit index 0..511
    const float bi = Bp[colb + r];
    const float bf = Bp[colb + 16 + r];
    const float bg = Bp[colb + 32 + r];
    const float bo = Bp[colb + 48 + r];

    // hoist the 16 c-loads so their latency overlaps the math below
    float cc[4][4];
#pragma unroll
    for (int i = 0; i < 4; ++i)
#pragma unroll
        for (int rr = 0; rr < 4; ++rr) {
            int row = bm * BM + wm * 64 + i * 16 + q * 4 + rr;
            cc[i][rr] = cst[(size_t)row * RNN + u];
        }

#define HLD 40   // h-xpose row stride: 80B rows (16B-aligned)
#pragma unroll
    for (int i = 0; i < 4; ++i) {
#pragma unroll
        for (int rr = 0; rr < 4; ++rr) {
            int rowl = wm * 64 + i * 16 + q * 4 + rr;       // row in block
            int row  = bm * BM + rowl;
            size_t cidx = (size_t)row * RNN + u;
            float gi = acc[i][0][rr] + bi;
            float gf = acc[i][1][rr] + bf;
            float gg = acc[i][2][rr] + bg;
            float go = acc[i][3][rr] + bo;
            float cn = sigmoidf_(gf) * cc[i][rr] + sigmoidf_(gi) * tanhf_(gg);
            float h  = sigmoidf_(go) * tanhf_(cn);
            cst[cidx] = cn;                                  // 64B segments
            if (en_out) outf[cidx] = h;
            sA[rowl * HLD + wn * 16 + r] = __float2bfloat16(h);
        }
    }
    __syncthreads();

    // coalesced h stores: 128 rows x 32 units bf16; 16B x 512 chunks
#pragma unroll
    for (int half = 0; half < 2; ++half) {
        int t2   = half * 256 + tid;       // 0..511
        int rowl = t2 >> 2;                // 0..127
        int c8   = (t2 & 3) * 8;           // 0,8,16,24
        uint4 v  = *(const uint4*)&sA[rowl * HLD + c8];
        int row  = bm * BM + rowl;
        int gcol = bn * 32 + c8;           // unit col within [0,512)
        *(uint4*)&hdst[(size_t)row * K2 + offh + gcol] = v;
    }
#undef HLD
}

// ---------------------------------------------------------------------------
// Workspace layout (all 16B-aligned; total 125,276,160 B):
//   c1   fp32 [12800][512]           26,214,400   offset 0
//   c2   fp32 [12800][512]           26,214,400   offset  26,214,400
//   A2a  bf16 [12800][1024]          26,214,400   offset  52,428,800
//   A2b  bf16 [12800][1024]          26,214,400   offset  78,643,200
//   W2Vt bf16 [20000][320]           12,800,000   offset 104,857,600
//   Wc1  bf16 [2048][832]             3,407,872   offset 117,657,600
//   Wc2  bf16 [2048][1024]            4,194,304   offset 121,065,472
//   Bp1  fp32 [2048]                      8,192   offset 125,259,776
//   Bp2  fp32 [2048]                      8,192   offset 125,267,968
// Only c1,c2 (52 MB) zeroed. A2 needs no init: t=0 dispatches skip the h
// K-region entirely (Kl truncation).
//
// Dispatch schedule (9 GEMM dispatches; cur(t)=t&1):
//   stage 0:      L1(0) alone        (role_base=1, z=1, Kl1=320)
//   stage s=1..7: [L2(s-1) || L1(s)] (role_base=0, z=2)
//       Asrc=A2[(s-1)&1]: L2 reads cols[0,1024), L1 reads cols[0,512) (RR ok)
//       hdst=A2[s&1]:     L2 writes cols[512,1024), L1 writes cols[0,512)
//       => disjoint writes, no read/write overlap: RACE-FREE.
//       Kl2 = (s==1 ? 512 : 1024)  [h2(-1)=0], Kl1 = 832.
//   stage 8:      L2(7) alone        (role_base=0, z=1, Kl2=1024, en_out=1)
// ---------------------------------------------------------------------------
extern "C" void kernel_launch(void* const* d_in, const int* in_sizes, int n_in,
                              void* d_out, int out_size, void* d_ws, size_t ws_size,
                              hipStream_t stream) {
    (void)in_sizes; (void)n_in; (void)out_size; (void)ws_size;
    const int*   sent = (const int*)d_in[0];
    const float* w2v  = (const float*)d_in[1];
    const float* Wih1 = (const float*)d_in[2];
    const float* Whh1 = (const float*)d_in[3];
    const float* bih1 = (const float*)d_in[4];
    const float* bhh1 = (const float*)d_in[5];
    const float* Wih2 = (const float*)d_in[6];
    const float* Whh2 = (const float*)d_in[7];
    const float* bih2 = (const float*)d_in[8];
    const float* bhh2 = (const float*)d_in[9];
    float* out = (float*)d_out;

    char* ws = (char*)d_ws;
    float* c1   = (float*)(ws);
    float* c2   = (float*)(ws + 26214400);
    bf16*  A2[2];
    A2[0] = (bf16*)(ws + 52428800);
    A2[1] = (bf16*)(ws + 78643200);
    bf16*  W2Vt = (bf16*) (ws + 104857600);
    bf16*  Wc1  = (bf16*) (ws + 117657600);
    bf16*  Wc2  = (bf16*) (ws + 121065472);
    float* Bp1  = (float*)(ws + 125259776);
    float* Bp2  = (float*)(ws + 125267968);

    // zero c1,c2 ONLY (ws is re-poisoned 0xAA before every call)
    hipMemsetAsync(ws, 0, 52428800, stream);

    convert_weights<<<dim3((NG * K2 + 255) / 256), dim3(256), 0, stream>>>(
        Wih1, Whh1, Wih2, Whh2, bih1, bhh1, bih2, bhh2, Wc1, Wc2, Bp1, Bp2);

    // one-time pre-tanh'd embedding table (replaces 8 per-step embed_steps)
    tanh_w2v<<<dim3(VOCAB), dim3(EMBP), 0, stream>>>(w2v, W2Vt);

    // stage 0: L1(0) alone, x-region only (h1(-1)=0)
    gemm_lstm<<<dim3(NG / BN, BROWS / BM, 1), dim3(256), 0, stream>>>(
        1, 0, W2Vt, sent,
        A2[1] /*unused*/, A2[0],
        Wc1, Wc2, Bp1, Bp2, c1, c2,
        (float*)nullptr, 0,
        EMBP /*Kl1*/, 0 /*Kl2 unused*/);

    // stages 1..7: merged [L2(s-1) || L1(s)]
    for (int s = 1; s <= 7; ++s) {
        gemm_lstm<<<dim3(NG / BN, BROWS / BM, 2), dim3(256), 0, stream>>>(
            0, s, W2Vt, sent,
            A2[(s - 1) & 1], A2[s & 1],
            Wc1, Wc2, Bp1, Bp2, c1, c2,
            (float*)nullptr, 0,
            K1 /*Kl1*/, (s == 1) ? RNN : K2 /*Kl2*/);
    }

    // stage 8: L2(7) alone, writes final h2 -> out (fp32)
    gemm_lstm<<<dim3(NG / BN, BROWS / BM, 1), dim3(256), 0, stream>>>(
        0, 0 /*t unused*/, W2Vt, sent,
        A2[1], A2[0],
        Wc1, Wc2, Bp1, Bp2, c1, c2,
        out, 1,
        K1 /*unused*/, K2 /*Kl2*/);
}

// Round 6
// 1011.162 us; speedup vs baseline: 1.4608x; 1.0254x over previous
//
#include <hip/hip_runtime.h>
#include <hip/hip_bf16.h>

// Problem constants (from reference): B=64, NCLS=200 -> BN rows = 12800
#define BROWS  12800
#define TSTEPS 8
#define EMB    300
#define EMBP   320          // EMB padded to /32, x-slot width
#define RNN    512
#define NG     2048         // 4*RNN gate width
#define K1     832          // EMBP + RNN  (layer-1 concat GEMM K), 13*64
#define K2     1024         // RNN + RNN   (layer-2 concat GEMM K), 16*64
#define VOCAB  20000

typedef short bf16x8 __attribute__((ext_vector_type(8)));   // 8 bf16 in 4 VGPRs (m89-verified operand type)
typedef float f32x4  __attribute__((ext_vector_type(4)));
typedef __hip_bfloat16 bf16;

__device__ __forceinline__ float sigmoidf_(float x) { return 1.f / (1.f + __expf(-x)); }
// exp-based tanh: exact saturation at +-inf, ~ulp-level error vs tanhf, one v_exp
__device__ __forceinline__ float tanhf_(float x)    { return 1.f - 2.f / (__expf(2.f * x) + 1.f); }

// async global->LDS, 16B per lane (m97). LDS dest = wave-uniform base + lane*16;
// the GLOBAL source address is per-lane (enables the W2Vt id-gather below).
__device__ __forceinline__ void gl_lds16(const bf16* g, bf16* l) {
    __builtin_amdgcn_global_load_lds(
        (const __attribute__((address_space(1))) void*)g,
        (__attribute__((address_space(3))) void*)l,
        16, 0, 0);
}

// ---------------------------------------------------------------------------
// Weight repack (round-3 proven): fp32 -> bf16, K-concat LINEAR row-major
// [N=2048][K], GATE-INTERLEAVED row permutation: output row n encodes
//   w = n&15 (unit), g = (n>>4)&3 (gate i,f,g,o), b = n>>6 (unit group)
//   original row = g*512 + b*16 + w
// => each wave's 64-col span = [i|f|g|o] of the same 16 units (epilogue needs
// no cross-lane exchange). Emits permuted combined biases Bp = bih+bhh.
// ---------------------------------------------------------------------------
__global__ void convert_weights(const float* __restrict__ Wih1, const float* __restrict__ Whh1,
                                const float* __restrict__ Wih2, const float* __restrict__ Whh2,
                                const float* __restrict__ bih1, const float* __restrict__ bhh1,
                                const float* __restrict__ bih2, const float* __restrict__ bhh2,
                                bf16* __restrict__ Wc1, bf16* __restrict__ Wc2,
                                float* __restrict__ Bp1, float* __restrict__ Bp2) {
    int idx = blockIdx.x * 256 + threadIdx.x;
    const int n1 = NG * K1;   // 1,703,936
    const int n2 = NG * K2;   // 2,097,152
    if (idx < n1) {
        int n = idx / K1, k = idx - n * K1;
        int on = ((n >> 4) & 3) * RNN + (n >> 6) * 16 + (n & 15);
        float v = 0.f;
        if (k < EMB)        v = Wih1[on * EMB + k];
        else if (k >= EMBP) v = Whh1[on * RNN + (k - EMBP)];
        Wc1[idx] = __float2bfloat16(v);
    }
    if (idx < n2) {
        int n = idx >> 10, k = idx & (K2 - 1);
        int on = ((n >> 4) & 3) * RNN + (n >> 6) * 16 + (n & 15);
        float v = (k < RNN) ? Wih2[on * RNN + k] : Whh2[on * RNN + (k - RNN)];
        Wc2[idx] = __float2bfloat16(v);
    }
    if (idx < NG) {
        int on = ((idx >> 4) & 3) * RNN + (idx >> 6) * 16 + (idx & 15);
        Bp1[idx] = bih1[on] + bhh1[on];
        Bp2[idx] = bih2[on] + bhh2[on];
    }
}

// ---------------------------------------------------------------------------
// One-time tanh(word2vec) table, bf16 [VOCAB][320] (cols 300..319 zero).
// L1's x-region staging gathers rows of this table directly via per-lane
// global_load_lds sources. Same numerics as embed_step: fp32 tanh -> bf16.
// ---------------------------------------------------------------------------
__global__ void tanh_w2v(const float* __restrict__ w2v, bf16* __restrict__ W2Vt) {
    int row = blockIdx.x;
    int col = threadIdx.x;                 // 0..319
    float v = (col < EMB) ? tanhf_(w2v[row * EMB + col]) : 0.f;
    W2Vt[(size_t)row * EMBP + col] = __float2bfloat16(v);
}

// ---------------------------------------------------------------------------
// Fused GEMM + LSTM cell update — VERIFIED 71us/dispatch inner structure.
// ROUNDS 8-10 POST-MORTEM (do not re-attempt): deep-pipeline variants
// (256^2, 8-wave, counted-vmcnt) all regressed to 89-123us — lockstep sync
// cost exceeds this structure's barrier-drain cost at K=13-16 tiles.
//
// ROUND-12 (verified 1037us): role-merged dispatches [L2(t) || L1(t+1)]
// (race-free: disjoint writes, no read/write overlap) + W2Vt x-gather.
// ROUND-13 (this round):
//  (a) PHASE-SPLIT K-loop with incremented pointers: x-phase / h-phase as
//      separate loops; per-c global pointers precomputed and advanced +64
//      per tile. Removes per-tile 64-bit addr recompute + region branch
//      from the hot loop (VALUBusy was 54%, the top pipe).
//  (b) Bijective XCD-chunked block swizzle (nwg%8==0): logical work
//      (role,bm,bn) = chunk-contiguous per XCD, bn-fastest preserved
//      INSIDE each chunk => same-bm adjacency (proven to matter) becomes
//      XCD-local; A-panels/W fetched once per XCD L2 instead of spread.
//      FETCH was 219MB vs ~99MB compulsory.
//  (c) czero flags replace the 52MB c1/c2 memset: first use of each
//      role's c-state substitutes constant 0 for the load (identical
//      numerics to loading memset zeros).
//
// __launch_bounds__(256,4): 128-reg budget (ROUND-7: (256,5) spills the
// 64-reg accumulator; current usage ~64 VGPR + 64 AGPR = at cap — do NOT
// add K-loop-live state). Block 256 thr = 4 waves; tile 128x128.
// ---------------------------------------------------------------------------
#define BM 128
#define BN 128

__global__ __launch_bounds__(256, 4) void gemm_lstm(
        int role_base, int t,
        const bf16* __restrict__ W2Vt, const int* __restrict__ sent,
        const bf16* __restrict__ Asrc,   // A2[cur] panel, ld = K2
        bf16* __restrict__ hdst,         // A2[prv], ld = K2; offh by role
        const bf16* __restrict__ Wc1, const bf16* __restrict__ Wc2,
        const float* __restrict__ Bp1, const float* __restrict__ Bp2,
        float* __restrict__ cst1, float* __restrict__ cst2,
        float* __restrict__ outf, int en_out,
        int Kl1, int Kl2, int cz1, int cz2) {
    __shared__ __attribute__((aligned(16))) bf16 sA[BM * 64];   // 16 KB (reused as h xpose buf)
    __shared__ __attribute__((aligned(16))) bf16 sB[BN * 64];   // 16 KB

    const int tid  = threadIdx.x;
    const int lane = tid & 63;
    const int wave = tid >> 6;
    const int wm   = wave >> 1, wn = wave & 1;

    // XCD-chunked bijective swizzle over the whole grid (nwg = 1600*z, %8==0).
    // Default HW round-robins consecutive raw ids over 8 XCDs; this remap
    // gives each XCD a contiguous logical chunk (bn-fastest inside).
    const int zdim  = (int)gridDim.z;
    const int chunk = (zdim * 1600) >> 3;
    const int raw   = blockIdx.x + (blockIdx.y << 4) + blockIdx.z * 1600;
    const int lgc   = (raw & 7) * chunk + (raw >> 3);
    int role, rem;
    if (zdim == 2) { role = (lgc >= 1600) ? 1 : 0; rem = lgc - (role ? 1600 : 0); }
    else           { role = role_base;             rem = lgc; }
    const int bn = rem & 15;               // gate-col block (fastest)
    const int bm = rem >> 4;               // row block

    // wave-uniform role plumbing
    const bf16*  W;  int ldw, Kl, ksplit, offh, czero;
    const float* Bp; float* cst;
    if (role) { W = Wc1; ldw = K1; Kl = Kl1; ksplit = EMBP; offh = 0;   Bp = Bp1; cst = cst1; czero = cz1; }
    else      { W = Wc2; ldw = K2; Kl = Kl2; ksplit = 0;    offh = RNN; Bp = Bp2; cst = cst2; czero = cz2; }

    f32x4 acc[4][4];
#pragma unroll
    for (int i = 0; i < 4; ++i)
#pragma unroll
        for (int j = 0; j < 4; ++j)
#pragma unroll
            for (int r = 0; r < 4; ++r) acc[i][j][r] = 0.f;

    const int r = lane & 15, q = lane >> 4;

    // staging geometry: chunk ch = c*256+tid; row = ch>>3;
    // global k-chunk = (ch&7)^(row&7)  (XOR swizzle, zero conflicts)
    int srow[4], scol[4];
#pragma unroll
    for (int c = 0; c < 4; ++c) {
        int ch = c * 256 + tid;
        srow[c] = ch >> 3;
        scol[c] = ((ch & 7) ^ (srow[c] & 7)) * 8;
    }

    const bf16* Wbase = W + (size_t)(bn * BN) * ldw;
    const bf16* Abase = Asrc + (size_t)(bm * BM) * K2;

    // per-c staging pointers, advanced +64 per tile (no per-tile addr math)
    const bf16* ap[4];
    const bf16* wp[4];
#pragma unroll
    for (int c = 0; c < 4; ++c)
        wp[c] = Wbase + (size_t)srow[c] * ldw + scol[c];
    if (role) {
#pragma unroll
        for (int c = 0; c < 4; ++c) {
            int id = sent[(size_t)(bm * BM + srow[c]) * TSTEPS + t];  // 8-lane broadcast
            ap[c] = W2Vt + (size_t)id * EMBP + scol[c];
        }
    } else {
#pragma unroll
        for (int c = 0; c < 4; ++c)
            ap[c] = Abase + (size_t)srow[c] * K2 + scol[c];
    }

    auto tile = [&]() {
#pragma unroll
        for (int c = 0; c < 4; ++c) {
            gl_lds16(ap[c], &sA[(c * 256 + tid) * 8]);
            gl_lds16(wp[c], &sB[(c * 256 + tid) * 8]);
            ap[c] += 64; wp[c] += 64;
        }
        __syncthreads();
#pragma unroll
        for (int kk = 0; kk < 2; ++kk) {
            const int kc = kk << 2;        // 0 or 4
            bf16x8 af[4], wf[4];
#pragma unroll
            for (int i = 0; i < 4; ++i)
                af[i] = *(const bf16x8*)(&sA[(wm * 64 + i * 16 + r) * 64 + (((q + kc) ^ (r & 7)) * 8)]);
#pragma unroll
            for (int j = 0; j < 4; ++j)
                wf[j] = *(const bf16x8*)(&sB[(wn * 64 + j * 16 + r) * 64 + (((q + kc) ^ (r & 7)) * 8)]);
#pragma unroll
            for (int i = 0; i < 4; ++i)
#pragma unroll
                for (int j = 0; j < 4; ++j)
                    acc[i][j] = __builtin_amdgcn_mfma_f32_16x16x32_bf16(
                        af[i], wf[j], acc[i][j], 0, 0, 0);
        }
        __syncthreads();
    };

    const int ntx = ksplit >> 6;            // x-region tiles (L1: 5, L2: 0)
    const int nth = (Kl - ksplit) >> 6;     // h-region tiles
    for (int tt = 0; tt < ntx; ++tt) tile();
    if (role) {                             // switch A source to h-region
#pragma unroll
        for (int c = 0; c < 4; ++c)
            ap[c] = Abase + (size_t)srow[c] * K2 + scol[c];
    }
    for (int tt = 0; tt < nth; ++tt) tile();
    // trailing barrier: all sA reads done -> safe to reuse as h buffer

    // ---- fused LSTM epilogue ----
    // C/D mapping (m89/m91-verified): col = lane&15, row = (lane>>4)*4 + reg
    const int colb = bn * BN + wn * 64;
    const int u    = (2 * bn + wn) * 16 + r;      // global unit index 0..511
    const float bi = Bp[colb + r];
    const float bf = Bp[colb + 16 + r];
    const float bg = Bp[colb + 32 + r];
    const float bo = Bp[colb + 48 + r];

    // hoist the 16 c-loads so their latency overlaps the math below
    // (czero: first use of this role's c-state -> constant 0, no load)
    float cc[4][4];
    if (czero) {
#pragma unroll
        for (int i = 0; i < 4; ++i)
#pragma unroll
            for (int rr = 0; rr < 4; ++rr) cc[i][rr] = 0.f;
    } else {
#pragma unroll
        for (int i = 0; i < 4; ++i)
#pragma unroll
            for (int rr = 0; rr < 4; ++rr) {
                int row = bm * BM + wm * 64 + i * 16 + q * 4 + rr;
                cc[i][rr] = cst[(size_t)row * RNN + u];
            }
    }

#define HLD 40   // h-xpose row stride: 80B rows (16B-aligned)
#pragma unroll
    for (int i = 0; i < 4; ++i) {
#pragma unroll
        for (int rr = 0; rr < 4; ++rr) {
            int rowl = wm * 64 + i * 16 + q * 4 + rr;       // row in block
            int row  = bm * BM + rowl;
            size_t cidx = (size_t)row * RNN + u;
            float gi = acc[i][0][rr] + bi;
            float gf = acc[i][1][rr] + bf;
            float gg = acc[i][2][rr] + bg;
            float go = acc[i][3][rr] + bo;
            float cn = sigmoidf_(gf) * cc[i][rr] + sigmoidf_(gi) * tanhf_(gg);
            float h  = sigmoidf_(go) * tanhf_(cn);
            cst[cidx] = cn;                                  // 64B segments
            if (en_out) outf[cidx] = h;
            sA[rowl * HLD + wn * 16 + r] = __float2bfloat16(h);
        }
    }
    __syncthreads();

    // coalesced h stores: 128 rows x 32 units bf16; 16B x 512 chunks
#pragma unroll
    for (int half = 0; half < 2; ++half) {
        int t2   = half * 256 + tid;       // 0..511
        int rowl = t2 >> 2;                // 0..127
        int c8   = (t2 & 3) * 8;           // 0,8,16,24
        uint4 v  = *(const uint4*)&sA[rowl * HLD + c8];
        int row  = bm * BM + rowl;
        int gcol = bn * 32 + c8;           // unit col within [0,512)
        *(uint4*)&hdst[(size_t)row * K2 + offh + gcol] = v;
    }
#undef HLD
}

// ---------------------------------------------------------------------------
// Workspace layout (all 16B-aligned; total 125,276,160 B):
//   c1   fp32 [12800][512]           26,214,400   offset 0
//   c2   fp32 [12800][512]           26,214,400   offset  26,214,400
//   A2a  bf16 [12800][1024]          26,214,400   offset  52,428,800
//   A2b  bf16 [12800][1024]          26,214,400   offset  78,643,200
//   W2Vt bf16 [20000][320]           12,800,000   offset 104,857,600
//   Wc1  bf16 [2048][832]             3,407,872   offset 117,657,600
//   Wc2  bf16 [2048][1024]            4,194,304   offset 121,065,472
//   Bp1  fp32 [2048]                      8,192   offset 125,259,776
//   Bp2  fp32 [2048]                      8,192   offset 125,267,968
// NO memset: c-state first use is czero-substituted (stage0 L1, s==1 L2);
// A2 needs no init (t=0 Kl truncation skips the h K-region entirely).
//
// Dispatch schedule (9 GEMM dispatches; cur(t)=t&1):
//   stage 0:      L1(0) alone        (role_base=1, z=1, Kl1=320, cz1=1)
//   stage s=1..7: [L2(s-1) || L1(s)] (role_base=0, z=2)
//       Asrc=A2[(s-1)&1]: L2 reads cols[0,1024), L1 reads cols[0,512) (RR ok)
//       hdst=A2[s&1]:     L2 writes cols[512,1024), L1 writes cols[0,512)
//       => disjoint writes, no read/write overlap: RACE-FREE.
//       Kl2 = (s==1 ? 512 : 1024) [h2(-1)=0], cz2 = (s==1), Kl1=832, cz1=0.
//   stage 8:      L2(7) alone        (role_base=0, z=1, Kl2=1024, en_out=1)
// ---------------------------------------------------------------------------
extern "C" void kernel_launch(void* const* d_in, const int* in_sizes, int n_in,
                              void* d_out, int out_size, void* d_ws, size_t ws_size,
                              hipStream_t stream) {
    (void)in_sizes; (void)n_in; (void)out_size; (void)ws_size;
    const int*   sent = (const int*)d_in[0];
    const float* w2v  = (const float*)d_in[1];
    const float* Wih1 = (const float*)d_in[2];
    const float* Whh1 = (const float*)d_in[3];
    const float* bih1 = (const float*)d_in[4];
    const float* bhh1 = (const float*)d_in[5];
    const float* Wih2 = (const float*)d_in[6];
    const float* Whh2 = (const float*)d_in[7];
    const float* bih2 = (const float*)d_in[8];
    const float* bhh2 = (const float*)d_in[9];
    float* out = (float*)d_out;

    char* ws = (char*)d_ws;
    float* c1   = (float*)(ws);
    float* c2   = (float*)(ws + 26214400);
    bf16*  A2[2];
    A2[0] = (bf16*)(ws + 52428800);
    A2[1] = (bf16*)(ws + 78643200);
    bf16*  W2Vt = (bf16*) (ws + 104857600);
    bf16*  Wc1  = (bf16*) (ws + 117657600);
    bf16*  Wc2  = (bf16*) (ws + 121065472);
    float* Bp1  = (float*)(ws + 125259776);
    float* Bp2  = (float*)(ws + 125267968);

    convert_weights<<<dim3((NG * K2 + 255) / 256), dim3(256), 0, stream>>>(
        Wih1, Whh1, Wih2, Whh2, bih1, bhh1, bih2, bhh2, Wc1, Wc2, Bp1, Bp2);

    // one-time pre-tanh'd embedding table
    tanh_w2v<<<dim3(VOCAB), dim3(EMBP), 0, stream>>>(w2v, W2Vt);

    // stage 0: L1(0) alone, x-region only (h1(-1)=0, c1(-1)=0)
    gemm_lstm<<<dim3(NG / BN, BROWS / BM, 1), dim3(256), 0, stream>>>(
        1, 0, W2Vt, sent,
        A2[1] /*unused*/, A2[0],
        Wc1, Wc2, Bp1, Bp2, c1, c2,
        (float*)nullptr, 0,
        EMBP /*Kl1*/, 0 /*Kl2 unused*/, 1 /*cz1*/, 0);

    // stages 1..7: merged [L2(s-1) || L1(s)]
    for (int s = 1; s <= 7; ++s) {
        gemm_lstm<<<dim3(NG / BN, BROWS / BM, 2), dim3(256), 0, stream>>>(
            0, s, W2Vt, sent,
            A2[(s - 1) & 1], A2[s & 1],
            Wc1, Wc2, Bp1, Bp2, c1, c2,
            (float*)nullptr, 0,
            K1 /*Kl1*/, (s == 1) ? RNN : K2 /*Kl2*/,
            0 /*cz1*/, (s == 1) ? 1 : 0 /*cz2*/);
    }

    // stage 8: L2(7) alone, writes final h2 -> out (fp32)
    gemm_lstm<<<dim3(NG / BN, BROWS / BM, 1), dim3(256), 0, stream>>>(
        0, 0 /*t unused*/, W2Vt, sent,
        A2[1], A2[0],
        Wc1, Wc2, Bp1, Bp2, c1, c2,
        out, 1,
        K1 /*unused*/, K2 /*Kl2*/, 0, 0);
}

// Round 8
// 991.092 us; speedup vs baseline: 1.4904x; 1.0202x over previous
//
#include <hip/hip_runtime.h>
#include <hip/hip_bf16.h>

// Problem constants (from reference): B=64, NCLS=200 -> BN rows = 12800
#define BROWS  12800
#define TSTEPS 8
#define EMB    300
#define EMBP   320          // EMB padded to /32, x-slot width
#define RNN    512
#define NG     2048         // 4*RNN gate width
#define K1     832          // EMBP + RNN  (layer-1 concat GEMM K), 13*64
#define K2     1024         // RNN + RNN   (layer-2 concat GEMM K), 16*64
#define VOCAB  20000

typedef short bf16x8 __attribute__((ext_vector_type(8)));   // 8 bf16 in 4 VGPRs (m89-verified operand type)
typedef float f32x4  __attribute__((ext_vector_type(4)));
typedef __hip_bfloat16 bf16;

__device__ __forceinline__ float sigmoidf_(float x) { return 1.f / (1.f + __expf(-x)); }
// exp-based tanh: exact saturation at +-inf, ~ulp-level error vs tanhf, one v_exp
__device__ __forceinline__ float tanhf_(float x)    { return 1.f - 2.f / (__expf(2.f * x) + 1.f); }

// async global->LDS, 16B/lane, offset arg ALWAYS 0.
// ROUND-7 LESSON (correctness failure, absmax 0.30): a NON-ZERO offset arg
// to __builtin_amdgcn_global_load_lds scrambles the staged tiles on gfx950
// (LDS-DMA offset semantics are not the documented global_load offset:N).
// K-advance must be expressed on the POINTER (compile-time literal; the
// compiler folds it into the instruction immediate itself).
#define GL16(p, l)                                                          \
    __builtin_amdgcn_global_load_lds(                                       \
        (const __attribute__((address_space(1))) void*)(p),                 \
        (__attribute__((address_space(3))) void*)(l), 16, 0, 0)

// ---------------------------------------------------------------------------
// Weight repack (round-3 proven): fp32 -> bf16, K-concat LINEAR row-major
// [N=2048][K], GATE-INTERLEAVED row permutation: output row n encodes
//   w = n&15 (unit), g = (n>>4)&3 (gate i,f,g,o), b = n>>6 (unit group)
//   original row = g*512 + b*16 + w
// => each wave's 64-col span = [i|f|g|o] of the same 16 units (epilogue needs
// no cross-lane exchange). Emits permuted combined biases Bp = bih+bhh.
// ---------------------------------------------------------------------------
__global__ void convert_weights(const float* __restrict__ Wih1, const float* __restrict__ Whh1,
                                const float* __restrict__ Wih2, const float* __restrict__ Whh2,
                                const float* __restrict__ bih1, const float* __restrict__ bhh1,
                                const float* __restrict__ bih2, const float* __restrict__ bhh2,
                                bf16* __restrict__ Wc1, bf16* __restrict__ Wc2,
                                float* __restrict__ Bp1, float* __restrict__ Bp2) {
    int idx = blockIdx.x * 256 + threadIdx.x;
    const int n1 = NG * K1;   // 1,703,936
    const int n2 = NG * K2;   // 2,097,152
    if (idx < n1) {
        int n = idx / K1, k = idx - n * K1;
        int on = ((n >> 4) & 3) * RNN + (n >> 6) * 16 + (n & 15);
        float v = 0.f;
        if (k < EMB)        v = Wih1[on * EMB + k];
        else if (k >= EMBP) v = Whh1[on * RNN + (k - EMBP)];
        Wc1[idx] = __float2bfloat16(v);
    }
    if (idx < n2) {
        int n = idx >> 10, k = idx & (K2 - 1);
        int on = ((n >> 4) & 3) * RNN + (n >> 6) * 16 + (n & 15);
        float v = (k < RNN) ? Wih2[on * RNN + k] : Whh2[on * RNN + (k - RNN)];
        Wc2[idx] = __float2bfloat16(v);
    }
    if (idx < NG) {
        int on = ((idx >> 4) & 3) * RNN + (idx >> 6) * 16 + (idx & 15);
        Bp1[idx] = bih1[on] + bhh1[on];
        Bp2[idx] = bih2[on] + bhh2[on];
    }
}

// ---------------------------------------------------------------------------
// One-time tanh(word2vec) table, bf16 [VOCAB][320] (cols 300..319 zero).
// L1's x-region staging gathers rows of this table directly via per-lane
// global_load_lds sources. Same numerics as embed_step: fp32 tanh -> bf16.
// ---------------------------------------------------------------------------
__global__ void tanh_w2v(const float* __restrict__ w2v, bf16* __restrict__ W2Vt) {
    int row = blockIdx.x;
    int col = threadIdx.x;                 // 0..319
    float v = (col < EMB) ? tanhf_(w2v[row * EMB + col]) : 0.f;
    W2Vt[(size_t)row * EMBP + col] = __float2bfloat16(v);
}

// ---------------------------------------------------------------------------
// Fused GEMM + LSTM — VERIFIED 71us/dispatch 2-barrier 128^2 structure.
// ROUNDS 8-10 POST-MORTEM (do not re-attempt): deep-pipeline variants all
// regressed (89-123us) — lockstep sync cost exceeds barrier-drain cost at
// K=13-16 tiles with a heavy fused epilogue.
// ROUND-12 (1037us): role-merged dispatches [L2(t) || L1(t+1)] + W2Vt gather.
// ROUND-13 (1011us): XCD-chunked swizzle (FETCH 219->143MB), czero.
// ROUND-14 FAILED: builtin offset arg != 0 scrambles LDS-DMA (see GL16).
// ROUND-15 (this round): same zero-VALU K-loop, K-advance as pointer+literal:
//  - 4 template instantiations give compile-time tile counts.
//  - K-loop FULLY UNROLLED; staging addr = base pointer + literal element
//    offset (compiler folds into the load's immediate; no ptr increments).
//  - ds_read via 4 precomputed base addrs (adA/adB per kk) + literal
//    2048*i byte offsets (algebra verified identical to round-6 indexing).
//  - L1 h-region pointers built between x-phase and h-phase; live pointer
//    set <=16 VGPRs (64 VGPR + 64 AGPR = the (256,4) cap; ROUND-7 LESSON:
//    never bound below the accumulator).
// Sync structure (stage; bar; read+MFMA; bar) is byte-identical to round 6.
// ---------------------------------------------------------------------------
#define BM 128
#define BN 128

// 8 staging loads for one K-tile: A from AP[0..3] + literal element offset
// AE, W from wp[0..3] + literal WE (array indices literal -> registers)
#define STAGE8(AP, AE, WE) do {                                             \
    GL16(AP[0] + (AE), &sA[(0 * 256 + tid) * 8]);                           \
    GL16(AP[1] + (AE), &sA[(1 * 256 + tid) * 8]);                           \
    GL16(AP[2] + (AE), &sA[(2 * 256 + tid) * 8]);                           \
    GL16(AP[3] + (AE), &sA[(3 * 256 + tid) * 8]);                           \
    GL16(wp[0] + (WE), &sB[(0 * 256 + tid) * 8]);                           \
    GL16(wp[1] + (WE), &sB[(1 * 256 + tid) * 8]);                           \
    GL16(wp[2] + (WE), &sB[(2 * 256 + tid) * 8]);                           \
    GL16(wp[3] + (WE), &sB[(3 * 256 + tid) * 8]);                           \
} while (0)

// barrier; 16 ds_read_b128 (imm offsets off adA/adB); 32 MFMA; barrier
#define COMPUTE() do {                                                      \
    __syncthreads();                                                        \
    _Pragma("unroll")                                                       \
    for (int kk = 0; kk < 2; ++kk) {                                        \
        bf16x8 af[4], wf[4];                                                \
        _Pragma("unroll")                                                   \
        for (int i = 0; i < 4; ++i)                                         \
            af[i] = *(const bf16x8*)(adA[kk] + i * 1024);                   \
        _Pragma("unroll")                                                   \
        for (int j = 0; j < 4; ++j)                                         \
            wf[j] = *(const bf16x8*)(adB[kk] + j * 1024);                   \
        _Pragma("unroll")                                                   \
        for (int i = 0; i < 4; ++i)                                         \
            _Pragma("unroll")                                               \
            for (int j = 0; j < 4; ++j)                                     \
                acc[i][j] = __builtin_amdgcn_mfma_f32_16x16x32_bf16(        \
                    af[i], wf[j], acc[i][j], 0, 0, 0);                      \
    }                                                                       \
    __syncthreads();                                                        \
} while (0)

// per-tile element offsets: one K-tile = 64 elements (128 B) along K
#define XT(n)  do { STAGE8(xp, (n) * 64, (n) * 64); COMPUTE(); } while (0)
#define HT1(n) do { STAGE8(hp, (n) * 64, (5 + (n)) * 64); COMPUTE(); } while (0)
#define HT2(n) do { STAGE8(hp, (n) * 64, (n) * 64); COMPUTE(); } while (0)

// NTH1: L1 h-region tiles (0 or 8). NTL2: L2 tiles (8 or 16).
// ZM: 0 = merged z=2 (both roles), 1 = L1-only, 2 = L2-only.
template<int NTH1, int NTL2, int ZM>
__global__ __launch_bounds__(256, 4) void gemm_lstm(
        int t,
        const bf16* __restrict__ W2Vt, const int* __restrict__ sent,
        const bf16* __restrict__ Asrc,   // A2[cur] panel, ld = K2
        bf16* __restrict__ hdst,         // A2[prv], ld = K2; offh by role
        const bf16* __restrict__ Wc1, const bf16* __restrict__ Wc2,
        const float* __restrict__ Bp1, const float* __restrict__ Bp2,
        float* __restrict__ cst1, float* __restrict__ cst2,
        float* __restrict__ outf, int en_out, int cz1, int cz2) {
    __shared__ __attribute__((aligned(16))) bf16 sA[BM * 64];   // 16 KB (reused as h xpose buf)
    __shared__ __attribute__((aligned(16))) bf16 sB[BN * 64];   // 16 KB

    const int tid  = threadIdx.x;
    const int lane = tid & 63;
    const int wave = tid >> 6;
    const int wm   = wave >> 1, wn = wave & 1;

    // XCD-chunked bijective swizzle (nwg%8==0): each XCD gets a contiguous
    // logical chunk, bn-fastest inside => same-bm adjacency is XCD-local.
    int role, rem;
    if (ZM == 0) {
        const int raw = blockIdx.x + (blockIdx.y << 4) + blockIdx.z * 1600;
        const int lgc = (raw & 7) * 400 + (raw >> 3);
        role = (lgc >= 1600) ? 1 : 0;
        rem  = lgc - (role ? 1600 : 0);
    } else {
        const int raw = blockIdx.x + (blockIdx.y << 4);
        rem  = (raw & 7) * 200 + (raw >> 3);
        role = (ZM == 1) ? 1 : 0;
    }
    const int bn = rem & 15;               // gate-col block (fastest)
    const int bm = rem >> 4;               // row block

    // wave-uniform role plumbing
    const bf16*  W;  int ldw, offh, czero;
    const float* Bp; float* cst;
    if (role) { W = Wc1; ldw = K1; offh = 0;   Bp = Bp1; cst = cst1; czero = cz1; }
    else      { W = Wc2; ldw = K2; offh = RNN; Bp = Bp2; cst = cst2; czero = cz2; }

    f32x4 acc[4][4];
#pragma unroll
    for (int i = 0; i < 4; ++i)
#pragma unroll
        for (int j = 0; j < 4; ++j)
#pragma unroll
            for (int rr = 0; rr < 4; ++rr) acc[i][j][rr] = 0.f;

    const int r = lane & 15, q = lane >> 4;

    // staging geometry: chunk ch = c*256+tid; row = ch>>3;
    // global k-chunk = (ch&7)^(row&7)  (XOR swizzle, zero bank conflicts)
    int srow[4], scol[4];
#pragma unroll
    for (int c = 0; c < 4; ++c) {
        int ch = c * 256 + tid;
        srow[c] = ch >> 3;
        scol[c] = ((ch & 7) ^ (srow[c] & 7)) * 8;
    }

    // LDS fragment read bases (per kk): all frag reads are +2048*i byte lits
    const bf16* adA[2];
    const bf16* adB[2];
#pragma unroll
    for (int kk = 0; kk < 2; ++kk) {
        int x = ((q + 4 * kk) ^ (r & 7)) * 8;
        adA[kk] = &sA[(wm * 64 + r) * 64 + x];
        adB[kk] = &sB[(wn * 64 + r) * 64 + x];
    }

    // W staging pointers (fixed; K-advance is the literal WE)
    const bf16* wp[4];
#pragma unroll
    for (int c = 0; c < 4; ++c)
        wp[c] = W + (size_t)(bn * BN + srow[c]) * ldw + scol[c];

    if (ZM == 1 || (ZM == 0 && role)) {
        // ---- L1 role: x-phase (5 tiles, W2Vt gather) then h-phase ----
        {
            const bf16* xp[4];
#pragma unroll
            for (int c = 0; c < 4; ++c) {
                int id = sent[(bm * BM + srow[c]) * TSTEPS + t];  // 8-lane bcast
                xp[c] = W2Vt + (size_t)id * EMBP + scol[c];
            }
            XT(0); XT(1); XT(2); XT(3); XT(4);
        }
        if (NTH1 > 0) {
            const bf16* hp[4];
#pragma unroll
            for (int c = 0; c < 4; ++c)
                hp[c] = Asrc + (size_t)(bm * BM + srow[c]) * K2 + scol[c];
            HT1(0); HT1(1); HT1(2); HT1(3); HT1(4); HT1(5); HT1(6); HT1(7);
        }
    } else {
        // ---- L2 role: 8 or 16 tiles straight from A2[cur] ----
        const bf16* hp[4];
#pragma unroll
        for (int c = 0; c < 4; ++c)
            hp[c] = Asrc + (size_t)(bm * BM + srow[c]) * K2 + scol[c];
        HT2(0); HT2(1); HT2(2); HT2(3); HT2(4); HT2(5); HT2(6); HT2(7);
        if (NTL2 == 16) {
            HT2(8); HT2(9); HT2(10); HT2(11); HT2(12); HT2(13); HT2(14); HT2(15);
        }
    }
    // trailing barrier (inside COMPUTE): sA reads done -> reuse as h buffer

    // ---- fused LSTM epilogue ----
    // C/D mapping (m89/m91-verified): col = lane&15, row = (lane>>4)*4 + reg
    const int colb = bn * BN + wn * 64;
    const int u    = (2 * bn + wn) * 16 + r;      // global unit index 0..511
    const float bi = Bp[colb + r];
    const float bf = Bp[colb + 16 + r];
    const float bg = Bp[colb + 32 + r];
    const float bo = Bp[colb + 48 + r];

    // hoist the 16 c-loads so their latency overlaps the math below
    // (czero: first use of this role's c-state -> constant 0, no load)
    float cc[4][4];
    if (czero) {
#pragma unroll
        for (int i = 0; i < 4; ++i)
#pragma unroll
            for (int rr = 0; rr < 4; ++rr) cc[i][rr] = 0.f;
    } else {
#pragma unroll
        for (int i = 0; i < 4; ++i)
#pragma unroll
            for (int rr = 0; rr < 4; ++rr) {
                int row = bm * BM + wm * 64 + i * 16 + q * 4 + rr;
                cc[i][rr] = cst[(size_t)row * RNN + u];
            }
    }

#define HLD 40   // h-xpose row stride: 80B rows (16B-aligned)
#pragma unroll
    for (int i = 0; i < 4; ++i) {
#pragma unroll
        for (int rr = 0; rr < 4; ++rr) {
            int rowl = wm * 64 + i * 16 + q * 4 + rr;       // row in block
            int row  = bm * BM + rowl;
            size_t cidx = (size_t)row * RNN + u;
            float gi = acc[i][0][rr] + bi;
            float gf = acc[i][1][rr] + bf;
            float gg = acc[i][2][rr] + bg;
            float go = acc[i][3][rr] + bo;
            float cn = sigmoidf_(gf) * cc[i][rr] + sigmoidf_(gi) * tanhf_(gg);
            float h  = sigmoidf_(go) * tanhf_(cn);
            cst[cidx] = cn;                                  // 64B segments
            if (en_out) outf[cidx] = h;
            sA[rowl * HLD + wn * 16 + r] = __float2bfloat16(h);
        }
    }
    __syncthreads();

    // coalesced h stores: 128 rows x 32 units bf16; 16B x 512 chunks
#pragma unroll
    for (int half = 0; half < 2; ++half) {
        int t2   = half * 256 + tid;       // 0..511
        int rowl = t2 >> 2;                // 0..127
        int c8   = (t2 & 3) * 8;           // 0,8,16,24
        uint4 v  = *(const uint4*)&sA[rowl * HLD + c8];
        int row  = bm * BM + rowl;
        int gcol = bn * 32 + c8;           // unit col within [0,512)
        *(uint4*)&hdst[(size_t)row * K2 + offh + gcol] = v;
    }
#undef HLD
}

// ---------------------------------------------------------------------------
// Workspace layout (all 16B-aligned; total 125,276,160 B):
//   c1   fp32 [12800][512]           26,214,400   offset 0
//   c2   fp32 [12800][512]           26,214,400   offset  26,214,400
//   A2a  bf16 [12800][1024]          26,214,400   offset  52,428,800
//   A2b  bf16 [12800][1024]          26,214,400   offset  78,643,200
//   W2Vt bf16 [20000][320]           12,800,000   offset 104,857,600
//   Wc1  bf16 [2048][832]             3,407,872   offset 117,657,600
//   Wc2  bf16 [2048][1024]            4,194,304   offset 121,065,472
//   Bp1  fp32 [2048]                      8,192   offset 125,259,776
//   Bp2  fp32 [2048]                      8,192   offset 125,267,968
// NO memset: c-state first use is czero-substituted (stage0 L1, s==1 L2);
// A2 needs no init (t=0 tile-count truncation skips the h K-region).
//
// Dispatch schedule (9 GEMM dispatches; cur(t)=t&1):
//   stage 0:      L1(0) alone        gemm_lstm<0,0,1>, cz1
//   stage 1:      [L2(0) || L1(1)]   gemm_lstm<8,8,0>, cz2 (L2 h1-only)
//   stage s=2..7: [L2(s-1) || L1(s)] gemm_lstm<8,16,0>
//       Asrc=A2[(s-1)&1]: L2 reads cols[0,1024), L1 reads cols[0,512) (RR ok)
//       hdst=A2[s&1]:     L2 writes cols[512,1024), L1 writes cols[0,512)
//       => disjoint writes, no read/write overlap: RACE-FREE.
//   stage 8:      L2(7) alone        gemm_lstm<0,16,2>, en_out
// ---------------------------------------------------------------------------
extern "C" void kernel_launch(void* const* d_in, const int* in_sizes, int n_in,
                              void* d_out, int out_size, void* d_ws, size_t ws_size,
                              hipStream_t stream) {
    (void)in_sizes; (void)n_in; (void)out_size; (void)ws_size;
    const int*   sent = (const int*)d_in[0];
    const float* w2v  = (const float*)d_in[1];
    const float* Wih1 = (const float*)d_in[2];
    const float* Whh1 = (const float*)d_in[3];
    const float* bih1 = (const float*)d_in[4];
    const float* bhh1 = (const float*)d_in[5];
    const float* Wih2 = (const float*)d_in[6];
    const float* Whh2 = (const float*)d_in[7];
    const float* bih2 = (const float*)d_in[8];
    const float* bhh2 = (const float*)d_in[9];
    float* out = (float*)d_out;

    char* ws = (char*)d_ws;
    float* c1   = (float*)(ws);
    float* c2   = (float*)(ws + 26214400);
    bf16*  A2[2];
    A2[0] = (bf16*)(ws + 52428800);
    A2[1] = (bf16*)(ws + 78643200);
    bf16*  W2Vt = (bf16*) (ws + 104857600);
    bf16*  Wc1  = (bf16*) (ws + 117657600);
    bf16*  Wc2  = (bf16*) (ws + 121065472);
    float* Bp1  = (float*)(ws + 125259776);
    float* Bp2  = (float*)(ws + 125267968);

    convert_weights<<<dim3((NG * K2 + 255) / 256), dim3(256), 0, stream>>>(
        Wih1, Whh1, Wih2, Whh2, bih1, bhh1, bih2, bhh2, Wc1, Wc2, Bp1, Bp2);

    // one-time pre-tanh'd embedding table
    tanh_w2v<<<dim3(VOCAB), dim3(EMBP), 0, stream>>>(w2v, W2Vt);

    const dim3 blk(256);
    const dim3 g1(NG / BN, BROWS / BM, 1);
    const dim3 g2(NG / BN, BROWS / BM, 2);

    // stage 0: L1(0) alone, x-region only (h1(-1)=0, c1(-1)=0)
    gemm_lstm<0, 0, 1><<<g1, blk, 0, stream>>>(
        0, W2Vt, sent, A2[1] /*unused*/, A2[0],
        Wc1, Wc2, Bp1, Bp2, c1, c2,
        (float*)nullptr, 0, 1 /*cz1*/, 0);

    // stage 1: [L2(0) || L1(1)]; L2 truncated to h1-region (h2(-1)=0, c2=0)
    gemm_lstm<8, 8, 0><<<g2, blk, 0, stream>>>(
        1, W2Vt, sent, A2[0], A2[1],
        Wc1, Wc2, Bp1, Bp2, c1, c2,
        (float*)nullptr, 0, 0, 1 /*cz2*/);

    // stages 2..7: merged [L2(s-1) || L1(s)]
    for (int s = 2; s <= 7; ++s) {
        gemm_lstm<8, 16, 0><<<g2, blk, 0, stream>>>(
            s, W2Vt, sent, A2[(s - 1) & 1], A2[s & 1],
            Wc1, Wc2, Bp1, Bp2, c1, c2,
            (float*)nullptr, 0, 0, 0);
    }

    // stage 8: L2(7) alone, writes final h2 -> out (fp32)
    gemm_lstm<0, 16, 2><<<g1, blk, 0, stream>>>(
        0, W2Vt, sent, A2[1], A2[0],
        Wc1, Wc2, Bp1, Bp2, c1, c2,
        out, 1, 0, 0);
}